// Round 1
// baseline (3724.789 us; speedup 1.0000x reference)
//
#include <hip/hip_runtime.h>
#include <cstdint>
#include <cstddef>

// ============================================================================
// ConditionalRBM sampler — bit-exact resimulation of the JAX reference.
//
// Round-2: latency-bound inner loops (VALUBusy 5% on k_udot; k_phase reads
// wave-uniform state from global inside a rolled loop). Fix: stage state
// chunks in LDS as [kk][i] for b128 broadcast reads, fully unroll kk,
// row-major state everywhere (coalesced writes), register-resident W row in
// k_udot. Accumulation order (ascending-k single-acc fma chain) unchanged.
//
// ASSUMPTION STACK (verified by round-1 evidence):
//  A1: jax_threefry_partitionable = True:
//      split(key,n)[i] = TF(key,(0,i)); bits32[j] = TF0(key,(0,j)) ^ TF1(key,(0,j))
//  A2: logistic(x) = 1/(1+exp(-x)), IEEE fdiv
//  A3: exp = XLA-CPU vectorized Cephes/Eigen pexp
//  A4: dot = ascending-k single-accumulator fma chain (exact 0/1 products)
//  A5: x = (dot + udot) + bias association
//  Output dtype: int32 0/1 (harness reads d_out as int32).
// ============================================================================

#pragma clang fp contract(off)

#define BATCH 8192
#define NU 64
#define NF 256   // num_v == num_h == 256
#define RT 16    // rows per block
#define KC 64    // k-chunk rows staged per LDS pass
#define THERM 24
#define NSAMP 8

// ---------------- Threefry-2x32 (JAX rotation/injection schedule) ----------
__host__ __device__ __forceinline__ void tf2x32(uint32_t k0, uint32_t k1,
                                                uint32_t x0, uint32_t x1,
                                                uint32_t* o0, uint32_t* o1) {
  uint32_t ks2 = k0 ^ k1 ^ 0x1BD11BDAu;
  x0 += k0; x1 += k1;
#define TFR(r) { x0 += x1; x1 = (x1 << (r)) | (x1 >> (32 - (r))); x1 ^= x0; }
  TFR(13) TFR(15) TFR(26) TFR(6)
  x0 += k1;  x1 += ks2 + 1u;
  TFR(17) TFR(29) TFR(16) TFR(24)
  x0 += ks2; x1 += k0 + 2u;
  TFR(13) TFR(15) TFR(26) TFR(6)
  x0 += k0;  x1 += k1 + 3u;
  TFR(17) TFR(29) TFR(16) TFR(24)
  x0 += k1;  x1 += ks2 + 4u;
  TFR(13) TFR(15) TFR(26) TFR(6)
  x0 += ks2; x1 += k0 + 5u;
#undef TFR
  *o0 = x0; *o1 = x1;
}

// ---------------- XLA-CPU expf (Cephes/Eigen polynomial) -------------------
__device__ __forceinline__ float xla_expf(float x) {
  float xc = fminf(x, 88.3762626647950f);
  xc = fmaxf(xc, -88.3762626647949f);
  float fx = floorf(__builtin_fmaf(xc, 1.44269504088896341f, 0.5f));
  float tmp = 0.693359375f * fx;          // separate rounding (contract off)
  float z = -2.12194440e-4f * fx;
  float r = xc - tmp;
  r = r - z;
  z = r * r;
  float y = __builtin_fmaf(r, 1.9875691500e-4f, 1.3981999507e-3f);
  y = __builtin_fmaf(y, r, 8.3334519073e-3f);
  y = __builtin_fmaf(y, r, 4.1665795894e-2f);
  y = __builtin_fmaf(y, r, 1.6666665459e-1f);
  y = __builtin_fmaf(y, r, 5.0000001201e-1f);
  y = __builtin_fmaf(y, z, r);
  y = y + 1.0f;
  int n = (int)fx;
  float p2 = __int_as_float((n + 127) << 23);
  float res = y * p2;
  return fmaxf(res, x);                   // Eigen pexp: pmax(res, original x)
}

__device__ __forceinline__ float sigmoid_ref(float x) {
  float e = xla_expf(-x);                 // negate exact
  return 1.0f / (1.0f + e);               // IEEE fdiv (no fast-math)
}

// bern: partitionable threefry bits -> uniform [0,1) -> (u < p)
__device__ __forceinline__ float bern_sample(uint32_t key0, uint32_t key1,
                                             uint32_t idx, float p) {
  uint32_t b0, b1;
  tf2x32(key0, key1, 0u, idx, &b0, &b1);  // counter = (hi=0, lo=flat_idx)
  uint32_t bits = b0 ^ b1;                // 32-bit path XORs both words
  float u = __uint_as_float((bits >> 9) | 0x3f800000u) - 1.0f;
  return (u < p) ? 1.0f : 0.0f;
}

// ---------------- kernels ---------------------------------------------------
__global__ void k_transpose(const float* __restrict__ Whv,
                            float* __restrict__ WhvT) {
  int j = threadIdx.x;  // hidden
  int k = blockIdx.x;   // visible
  WhvT[k * NF + j] = Whv[j * NF + k];
}

// out[row][j] = sum_k u[row][k] * W[j][k], ascending k (exact products).
// W row j lives in registers; u-chunk (RT rows x 64) broadcast from LDS.
__global__ __launch_bounds__(256, 2) void k_udot(const float* __restrict__ U,
                                                 const float* __restrict__ W,
                                                 float* __restrict__ out) {
  __shared__ __align__(16) float Ulds[NU * RT];   // [k][i], 4 KiB
  const int j = threadIdx.x;
  const int i0 = blockIdx.x * RT;
  const int si = j & 15;          // row within tile
  const int sg = j >> 4;          // 4-col group (16 groups cover 64 cols)
  {
    float4 u4 = *(const float4*)(U + (size_t)(i0 + si) * NU + sg * 4);
    Ulds[(sg * 4 + 0) * RT + si] = u4.x;
    Ulds[(sg * 4 + 1) * RT + si] = u4.y;
    Ulds[(sg * 4 + 2) * RT + si] = u4.z;
    Ulds[(sg * 4 + 3) * RT + si] = u4.w;
  }
  // W row j -> registers (256B/lane, L2-hot after first blocks)
  float wreg[NU];
  const float4* wr4 = (const float4*)(W + (size_t)j * NU);
#pragma unroll
  for (int r = 0; r < NU / 4; ++r) {
    float4 t = wr4[r];
    wreg[4 * r + 0] = t.x; wreg[4 * r + 1] = t.y;
    wreg[4 * r + 2] = t.z; wreg[4 * r + 3] = t.w;
  }
  __syncthreads();
  float acc[RT];
#pragma unroll
  for (int i = 0; i < RT; ++i) acc[i] = 0.0f;
#pragma unroll
  for (int kk = 0; kk < NU; ++kk) {
    const float w = wreg[kk];
    const float4 s0 = *(const float4*)(&Ulds[kk * RT + 0]);
    const float4 s1 = *(const float4*)(&Ulds[kk * RT + 4]);
    const float4 s2 = *(const float4*)(&Ulds[kk * RT + 8]);
    const float4 s3 = *(const float4*)(&Ulds[kk * RT + 12]);
    acc[0]  = __builtin_fmaf(s0.x, w, acc[0]);
    acc[1]  = __builtin_fmaf(s0.y, w, acc[1]);
    acc[2]  = __builtin_fmaf(s0.z, w, acc[2]);
    acc[3]  = __builtin_fmaf(s0.w, w, acc[3]);
    acc[4]  = __builtin_fmaf(s1.x, w, acc[4]);
    acc[5]  = __builtin_fmaf(s1.y, w, acc[5]);
    acc[6]  = __builtin_fmaf(s1.z, w, acc[6]);
    acc[7]  = __builtin_fmaf(s1.w, w, acc[7]);
    acc[8]  = __builtin_fmaf(s2.x, w, acc[8]);
    acc[9]  = __builtin_fmaf(s2.y, w, acc[9]);
    acc[10] = __builtin_fmaf(s2.z, w, acc[10]);
    acc[11] = __builtin_fmaf(s2.w, w, acc[11]);
    acc[12] = __builtin_fmaf(s3.x, w, acc[12]);
    acc[13] = __builtin_fmaf(s3.y, w, acc[13]);
    acc[14] = __builtin_fmaf(s3.z, w, acc[14]);
    acc[15] = __builtin_fmaf(s3.w, w, acc[15]);
  }
#pragma unroll
  for (int i = 0; i < RT; ++i)
    out[(size_t)(i0 + i) * NF + j] = acc[i];
}

// v0 = bern(ks[0], sigmoid(uv + bv)); row-major state write (coalesced)
__global__ __launch_bounds__(256) void k_init(const float* __restrict__ uv,
                                              const float* __restrict__ bv,
                                              float* __restrict__ V,
                                              uint32_t key0, uint32_t key1) {
  int j = threadIdx.x;
  int i0 = blockIdx.x * RT;
  float b = bv[j];
#pragma unroll
  for (int i = 0; i < RT; ++i) {
    int row = i0 + i;
    uint32_t idx = (uint32_t)(row * NF + j);
    float x = uv[idx] + b;                // (dot) + bias : single add
    float p = sigmoid_ref(x);
    V[idx] = bern_sample(key0, key1, idx, p);
  }
}

// One Gibbs half-step: O = bern(key, sigmoid((S @ W) + C + bias))
// S: prev state row-major [8192][256] (0/1); W: [256 k][256 j] (k-major);
// C: u-dot [8192][256]; O: next state row-major; smp: optional int32 samples.
// LDS: W chunk 64KiB + S chunk 4KiB (layout [kk][i] -> b128 broadcasts).
__global__ __launch_bounds__(256, 2) void k_phase(const float* __restrict__ S,
                                                  const float* __restrict__ W,
                                                  const float* __restrict__ C,
                                                  const float* __restrict__ bias,
                                                  float* __restrict__ O,
                                                  int* __restrict__ smp,
                                                  uint32_t key0, uint32_t key1) {
  __shared__ __align__(16) float Wlds[KC * NF];   // 64 KiB
  __shared__ __align__(16) float Slds[KC * RT];   // 4 KiB, [kk][i]
  const int j = threadIdx.x;
  const int i0 = blockIdx.x * RT;
  const int si = j & 15;
  const int sg = j >> 4;
  float acc[RT];
#pragma unroll
  for (int i = 0; i < RT; ++i) acc[i] = 0.0f;

  for (int kc = 0; kc < NF; kc += KC) {
    __syncthreads();
    // stage W rows [kc, kc+KC) -> Wlds (identity copy, coalesced float4)
    const float4* src4 = (const float4*)(W + (size_t)kc * NF);
    float4* l4 = (float4*)Wlds;
#pragma unroll
    for (int r = 0; r < 16; ++r) l4[r * 256 + j] = src4[r * 256 + j];
    // stage S chunk: rows i0..i0+15, cols kc..kc+63 -> Slds[kk][i]
    {
      float4 u4 = *(const float4*)(S + (size_t)(i0 + si) * NF + kc + sg * 4);
      Slds[(sg * 4 + 0) * RT + si] = u4.x;
      Slds[(sg * 4 + 1) * RT + si] = u4.y;
      Slds[(sg * 4 + 2) * RT + si] = u4.z;
      Slds[(sg * 4 + 3) * RT + si] = u4.w;
    }
    __syncthreads();
#pragma unroll
    for (int kk = 0; kk < KC; ++kk) {
      const float w = Wlds[kk * NF + j];              // 2 lanes/bank: free
      const float4 s0 = *(const float4*)(&Slds[kk * RT + 0]);   // broadcasts
      const float4 s1 = *(const float4*)(&Slds[kk * RT + 4]);
      const float4 s2 = *(const float4*)(&Slds[kk * RT + 8]);
      const float4 s3 = *(const float4*)(&Slds[kk * RT + 12]);
      acc[0]  = __builtin_fmaf(s0.x, w, acc[0]);      // exact product (0/1)
      acc[1]  = __builtin_fmaf(s0.y, w, acc[1]);
      acc[2]  = __builtin_fmaf(s0.z, w, acc[2]);
      acc[3]  = __builtin_fmaf(s0.w, w, acc[3]);
      acc[4]  = __builtin_fmaf(s1.x, w, acc[4]);
      acc[5]  = __builtin_fmaf(s1.y, w, acc[5]);
      acc[6]  = __builtin_fmaf(s1.z, w, acc[6]);
      acc[7]  = __builtin_fmaf(s1.w, w, acc[7]);
      acc[8]  = __builtin_fmaf(s2.x, w, acc[8]);
      acc[9]  = __builtin_fmaf(s2.y, w, acc[9]);
      acc[10] = __builtin_fmaf(s2.z, w, acc[10]);
      acc[11] = __builtin_fmaf(s2.w, w, acc[11]);
      acc[12] = __builtin_fmaf(s3.x, w, acc[12]);
      acc[13] = __builtin_fmaf(s3.y, w, acc[13]);
      acc[14] = __builtin_fmaf(s3.z, w, acc[14]);
      acc[15] = __builtin_fmaf(s3.w, w, acc[15]);
    }
  }

  const float b = bias[j];
#pragma unroll
  for (int i = 0; i < RT; ++i) {
    int row = i0 + i;
    uint32_t idx = (uint32_t)(row * NF + j);
    float x = (acc[i] + C[idx]) + b;      // (dot + udot) + bias
    float p = sigmoid_ref(x);
    float v = bern_sample(key0, key1, idx, p);
    O[idx] = v;                           // coalesced row-major store
    if (smp) smp[idx] = (v != 0.0f) ? 1 : 0;
  }
}

// ---------------- launch ----------------------------------------------------
extern "C" void kernel_launch(void* const* d_in, const int* in_sizes, int n_in,
                              void* d_out, int out_size, void* d_ws, size_t ws_size,
                              hipStream_t stream) {
  const float* u_state = (const float*)d_in[0];  // [8192][64] 0/1 floats
  const float* Wvu     = (const float*)d_in[1];  // [256][64]
  const float* Whu     = (const float*)d_in[2];  // [256][64]
  const float* Whv     = (const float*)d_in[3];  // [256][256]
  const float* bv      = (const float*)d_in[4];  // [256]
  const float* bh      = (const float*)d_in[5];  // [256]
  int* out = (int*)d_out;                        // [8][8192][256] as int32 0/1

  // workspace layout (floats); total 8,454,144 f32 = 33.8 MB
  float* ws   = (float*)d_ws;
  float* WhvT = ws;                        // 65536
  float* uh   = WhvT + NF * NF;            // 8192*256
  float* uv   = uh + (size_t)BATCH * NF;
  float* V    = uv + (size_t)BATCH * NF;   // state, row-major [8192][256]
  float* H    = V + (size_t)BATCH * NF;

  // ---- host-side key schedule (pure CPU, deterministic) ----
  uint32_t s0[THERM + NSAMP + 1], s1[THERM + NSAMP + 1];
  for (uint32_t i = 0; i < THERM + NSAMP + 1; ++i)
    tf2x32(0u, 1u, 0u, i, &s0[i], &s1[i]);

  k_transpose<<<NF, NF, 0, stream>>>(Whv, WhvT);
  k_udot<<<BATCH / RT, NF, 0, stream>>>(u_state, Whu, uh);   // u @ Whu.T
  k_udot<<<BATCH / RT, NF, 0, stream>>>(u_state, Wvu, uv);   // u @ Wvu.T
  k_init<<<BATCH / RT, NF, 0, stream>>>(uv, bv, V, s0[0], s1[0]);

  for (int t = 0; t < THERM + NSAMP; ++t) {
    uint32_t kh0, kh1, kv0, kv1;
    tf2x32(s0[1 + t], s1[1 + t], 0u, 0u, &kh0, &kh1);
    tf2x32(s0[1 + t], s1[1 + t], 0u, 1u, &kv0, &kv1);
    int* smp = (t >= THERM) ? out + (size_t)(t - THERM) * BATCH * NF : (int*)nullptr;
    // h = bern(k1, sigmoid(v @ Whv.T + uh + bh))
    k_phase<<<BATCH / RT, NF, 0, stream>>>(V, WhvT, uh, bh, H, (int*)nullptr, kh0, kh1);
    // v = bern(k2, sigmoid(h @ Whv + uv + bv)) ; emit sample when t>=THERM
    k_phase<<<BATCH / RT, NF, 0, stream>>>(H, Whv, uv, bv, V, smp, kv0, kv1);
  }
  (void)in_sizes; (void)n_in; (void)out_size; (void)ws_size;
}

// Round 2
// 2132.848 us; speedup vs baseline: 1.7464x; 1.7464x over previous
//
#include <hip/hip_runtime.h>
#include <cstdint>
#include <cstddef>

// ============================================================================
// ConditionalRBM sampler — bit-exact resimulation of the JAX reference.
//
// Round-2 post-mortem: LDS-broadcast state reads put the state stream on the
// LDS pipe (0.24 fma/byte -> LDS-bound) and 68KiB LDS pinned occupancy at
// 2 blocks/CU (Occupancy 20%, VALUBusy 21%). Round-3: NO LDS at all.
//  - state transposed [K][BATCH]: 8 state floats/kk = one uniform 32B VMEM
//    read per wave (L1 line broadcast, off the VALU/LDS pipes)
//  - W rows read directly from global (coalesced, 256KB fits L2; L1-hot
//    since all blocks stream the same rows)
//  - RT=8 -> 1024 blocks = 4 blocks/CU = 4 waves/SIMD; no barriers to drain
// Accumulation order per output unchanged: single ascending-k fma chain.
//
// ASSUMPTION STACK (verified bit-exact in earlier rounds):
//  A1: jax_threefry_partitionable = True:
//      split(key,n)[i] = TF(key,(0,i)); bits32[j] = TF0(key,(0,j)) ^ TF1(key,(0,j))
//  A2: logistic(x) = 1/(1+exp(-x)), IEEE fdiv
//  A3: exp = XLA-CPU vectorized Cephes/Eigen pexp
//  A4: dot = ascending-k single-accumulator fma chain (exact 0/1 products)
//  A5: x = (dot + udot) + bias association
//  Output dtype: int32 0/1 (harness reads d_out as int32).
// ============================================================================

#pragma clang fp contract(off)

#define BATCH 8192
#define NU 64
#define NF 256   // num_v == num_h == 256
#define RT 8     // rows per thread in k_phase (grid = 1024 blocks)
#define RTI 16   // rows per block in k_init / k_udot
#define THERM 24
#define NSAMP 8

// ---------------- Threefry-2x32 (JAX rotation/injection schedule) ----------
__host__ __device__ __forceinline__ void tf2x32(uint32_t k0, uint32_t k1,
                                                uint32_t x0, uint32_t x1,
                                                uint32_t* o0, uint32_t* o1) {
  uint32_t ks2 = k0 ^ k1 ^ 0x1BD11BDAu;
  x0 += k0; x1 += k1;
#define TFR(r) { x0 += x1; x1 = (x1 << (r)) | (x1 >> (32 - (r))); x1 ^= x0; }
  TFR(13) TFR(15) TFR(26) TFR(6)
  x0 += k1;  x1 += ks2 + 1u;
  TFR(17) TFR(29) TFR(16) TFR(24)
  x0 += ks2; x1 += k0 + 2u;
  TFR(13) TFR(15) TFR(26) TFR(6)
  x0 += k0;  x1 += k1 + 3u;
  TFR(17) TFR(29) TFR(16) TFR(24)
  x0 += k1;  x1 += ks2 + 4u;
  TFR(13) TFR(15) TFR(26) TFR(6)
  x0 += ks2; x1 += k0 + 5u;
#undef TFR
  *o0 = x0; *o1 = x1;
}

// ---------------- XLA-CPU expf (Cephes/Eigen polynomial) -------------------
__device__ __forceinline__ float xla_expf(float x) {
  float xc = fminf(x, 88.3762626647950f);
  xc = fmaxf(xc, -88.3762626647949f);
  float fx = floorf(__builtin_fmaf(xc, 1.44269504088896341f, 0.5f));
  float tmp = 0.693359375f * fx;          // separate rounding (contract off)
  float z = -2.12194440e-4f * fx;
  float r = xc - tmp;
  r = r - z;
  z = r * r;
  float y = __builtin_fmaf(r, 1.9875691500e-4f, 1.3981999507e-3f);
  y = __builtin_fmaf(y, r, 8.3334519073e-3f);
  y = __builtin_fmaf(y, r, 4.1665795894e-2f);
  y = __builtin_fmaf(y, r, 1.6666665459e-1f);
  y = __builtin_fmaf(y, r, 5.0000001201e-1f);
  y = __builtin_fmaf(y, z, r);
  y = y + 1.0f;
  int n = (int)fx;
  float p2 = __int_as_float((n + 127) << 23);
  float res = y * p2;
  return fmaxf(res, x);                   // Eigen pexp: pmax(res, original x)
}

__device__ __forceinline__ float sigmoid_ref(float x) {
  float e = xla_expf(-x);                 // negate exact
  return 1.0f / (1.0f + e);               // IEEE fdiv (no fast-math)
}

// bern: partitionable threefry bits -> uniform [0,1) -> (u < p)
__device__ __forceinline__ float bern_sample(uint32_t key0, uint32_t key1,
                                             uint32_t idx, float p) {
  uint32_t b0, b1;
  tf2x32(key0, key1, 0u, idx, &b0, &b1);  // counter = (hi=0, lo=flat_idx)
  uint32_t bits = b0 ^ b1;                // 32-bit path XORs both words
  float u = __uint_as_float((bits >> 9) | 0x3f800000u) - 1.0f;
  return (u < p) ? 1.0f : 0.0f;
}

// ---------------- kernels ---------------------------------------------------
__global__ void k_transpose(const float* __restrict__ Whv,
                            float* __restrict__ WhvT) {
  int j = threadIdx.x;  // hidden
  int k = blockIdx.x;   // visible
  WhvT[k * NF + j] = Whv[j * NF + k];
}

// out[row][j] = sum_k u[row][k] * W[j][k], ascending k (exact products).
// W row j lives in registers; u-chunk (RTI rows x 64) broadcast from LDS.
__global__ __launch_bounds__(256, 2) void k_udot(const float* __restrict__ U,
                                                 const float* __restrict__ W,
                                                 float* __restrict__ out) {
  __shared__ __align__(16) float Ulds[NU * RTI];  // [k][i], 4 KiB
  const int j = threadIdx.x;
  const int i0 = blockIdx.x * RTI;
  const int si = j & 15;          // row within tile
  const int sg = j >> 4;          // 4-col group (16 groups cover 64 cols)
  {
    float4 u4 = *(const float4*)(U + (size_t)(i0 + si) * NU + sg * 4);
    Ulds[(sg * 4 + 0) * RTI + si] = u4.x;
    Ulds[(sg * 4 + 1) * RTI + si] = u4.y;
    Ulds[(sg * 4 + 2) * RTI + si] = u4.z;
    Ulds[(sg * 4 + 3) * RTI + si] = u4.w;
  }
  float wreg[NU];
  const float4* wr4 = (const float4*)(W + (size_t)j * NU);
#pragma unroll
  for (int r = 0; r < NU / 4; ++r) {
    float4 t = wr4[r];
    wreg[4 * r + 0] = t.x; wreg[4 * r + 1] = t.y;
    wreg[4 * r + 2] = t.z; wreg[4 * r + 3] = t.w;
  }
  __syncthreads();
  float acc[RTI];
#pragma unroll
  for (int i = 0; i < RTI; ++i) acc[i] = 0.0f;
#pragma unroll
  for (int kk = 0; kk < NU; ++kk) {
    const float w = wreg[kk];
    const float4 s0 = *(const float4*)(&Ulds[kk * RTI + 0]);
    const float4 s1 = *(const float4*)(&Ulds[kk * RTI + 4]);
    const float4 s2 = *(const float4*)(&Ulds[kk * RTI + 8]);
    const float4 s3 = *(const float4*)(&Ulds[kk * RTI + 12]);
    acc[0]  = __builtin_fmaf(s0.x, w, acc[0]);
    acc[1]  = __builtin_fmaf(s0.y, w, acc[1]);
    acc[2]  = __builtin_fmaf(s0.z, w, acc[2]);
    acc[3]  = __builtin_fmaf(s0.w, w, acc[3]);
    acc[4]  = __builtin_fmaf(s1.x, w, acc[4]);
    acc[5]  = __builtin_fmaf(s1.y, w, acc[5]);
    acc[6]  = __builtin_fmaf(s1.z, w, acc[6]);
    acc[7]  = __builtin_fmaf(s1.w, w, acc[7]);
    acc[8]  = __builtin_fmaf(s2.x, w, acc[8]);
    acc[9]  = __builtin_fmaf(s2.y, w, acc[9]);
    acc[10] = __builtin_fmaf(s2.z, w, acc[10]);
    acc[11] = __builtin_fmaf(s2.w, w, acc[11]);
    acc[12] = __builtin_fmaf(s3.x, w, acc[12]);
    acc[13] = __builtin_fmaf(s3.y, w, acc[13]);
    acc[14] = __builtin_fmaf(s3.z, w, acc[14]);
    acc[15] = __builtin_fmaf(s3.w, w, acc[15]);
  }
#pragma unroll
  for (int i = 0; i < RTI; ++i)
    out[(size_t)(i0 + i) * NF + j] = acc[i];   // row-major C (coalesced)
}

// v0 = bern(ks[0], sigmoid(uv + bv)); writes transposed state Vt[j][row]
__global__ __launch_bounds__(256) void k_init(const float* __restrict__ uv,
                                              const float* __restrict__ bv,
                                              float* __restrict__ Vt,
                                              uint32_t key0, uint32_t key1) {
  int j = threadIdx.x;
  int i0 = blockIdx.x * RTI;
  float b = bv[j];
  float vals[RTI];
#pragma unroll
  for (int i = 0; i < RTI; ++i) {
    int row = i0 + i;
    uint32_t idx = (uint32_t)(row * NF + j);
    float x = uv[idx] + b;                // (dot) + bias : single add
    float p = sigmoid_ref(x);
    vals[i] = bern_sample(key0, key1, idx, p);
  }
  float4* dst = (float4*)(Vt + (size_t)j * BATCH + i0);
#pragma unroll
  for (int q = 0; q < RTI / 4; ++q)
    dst[q] = make_float4(vals[4 * q], vals[4 * q + 1], vals[4 * q + 2], vals[4 * q + 3]);
}

// One Gibbs half-step: O = bern(key, sigmoid((St^T @ W) + C + bias))
// St: prev state transposed [256 k][8192 i]; W: [256 k][256 j] k-major;
// C: u-dot row-major [8192][256]; Ot: next state transposed; smp: int32 out.
// No LDS, no barriers: W rows via coalesced L1/L2 reads, state via uniform
// 32B VMEM broadcasts. 1024 blocks -> 4 blocks/CU -> 4 waves/SIMD.
__global__ __launch_bounds__(256, 4) void k_phase(const float* __restrict__ St,
                                                  const float* __restrict__ W,
                                                  const float* __restrict__ C,
                                                  const float* __restrict__ bias,
                                                  float* __restrict__ Ot,
                                                  int* __restrict__ smp,
                                                  uint32_t key0, uint32_t key1) {
  const int j = threadIdx.x;
  const int i0 = blockIdx.x * RT;
  float acc[RT];
#pragma unroll
  for (int i = 0; i < RT; ++i) acc[i] = 0.0f;

  const float* pw = W + j;        // column j of W, stride NF
  const float* ps = St + i0;      // rows i0..i0+7, stride BATCH per k
#pragma unroll 8
  for (int k = 0; k < NF; ++k) {
    const float w = pw[(size_t)k * NF];                       // coalesced
    const float4 s0 = *(const float4*)(ps + (size_t)k * BATCH);      // uniform
    const float4 s1 = *(const float4*)(ps + (size_t)k * BATCH + 4);  // uniform
    acc[0] = __builtin_fmaf(s0.x, w, acc[0]);   // exact product (0/1)
    acc[1] = __builtin_fmaf(s0.y, w, acc[1]);
    acc[2] = __builtin_fmaf(s0.z, w, acc[2]);
    acc[3] = __builtin_fmaf(s0.w, w, acc[3]);
    acc[4] = __builtin_fmaf(s1.x, w, acc[4]);
    acc[5] = __builtin_fmaf(s1.y, w, acc[5]);
    acc[6] = __builtin_fmaf(s1.z, w, acc[6]);
    acc[7] = __builtin_fmaf(s1.w, w, acc[7]);
  }

  const float b = bias[j];
  float vals[RT];
#pragma unroll
  for (int i = 0; i < RT; ++i) {
    int row = i0 + i;
    uint32_t idx = (uint32_t)(row * NF + j);
    float x = (acc[i] + C[idx]) + b;      // (dot + udot) + bias
    float p = sigmoid_ref(x);
    vals[i] = bern_sample(key0, key1, idx, p);
  }
  float4* dst = (float4*)(Ot + (size_t)j * BATCH + i0);
  dst[0] = make_float4(vals[0], vals[1], vals[2], vals[3]);
  dst[1] = make_float4(vals[4], vals[5], vals[6], vals[7]);
  if (smp) {
#pragma unroll
    for (int i = 0; i < RT; ++i)
      smp[(size_t)(i0 + i) * NF + j] = (vals[i] != 0.0f) ? 1 : 0;  // int32
  }
}

// ---------------- launch ----------------------------------------------------
extern "C" void kernel_launch(void* const* d_in, const int* in_sizes, int n_in,
                              void* d_out, int out_size, void* d_ws, size_t ws_size,
                              hipStream_t stream) {
  const float* u_state = (const float*)d_in[0];  // [8192][64] 0/1 floats
  const float* Wvu     = (const float*)d_in[1];  // [256][64]
  const float* Whu     = (const float*)d_in[2];  // [256][64]
  const float* Whv     = (const float*)d_in[3];  // [256][256]
  const float* bv      = (const float*)d_in[4];  // [256]
  const float* bh      = (const float*)d_in[5];  // [256]
  int* out = (int*)d_out;                        // [8][8192][256] as int32 0/1

  // workspace layout (floats); total 8,454,144 f32 = 33.8 MB
  float* ws   = (float*)d_ws;
  float* WhvT = ws;                        // 65536
  float* uh   = WhvT + NF * NF;            // row-major [8192][256]
  float* uv   = uh + (size_t)BATCH * NF;
  float* Vt   = uv + (size_t)BATCH * NF;   // state, transposed [256][8192]
  float* Ht   = Vt + (size_t)BATCH * NF;

  // ---- host-side key schedule (pure CPU, deterministic) ----
  uint32_t s0[THERM + NSAMP + 1], s1[THERM + NSAMP + 1];
  for (uint32_t i = 0; i < THERM + NSAMP + 1; ++i)
    tf2x32(0u, 1u, 0u, i, &s0[i], &s1[i]);

  k_transpose<<<NF, NF, 0, stream>>>(Whv, WhvT);
  k_udot<<<BATCH / RTI, NF, 0, stream>>>(u_state, Whu, uh);   // u @ Whu.T
  k_udot<<<BATCH / RTI, NF, 0, stream>>>(u_state, Wvu, uv);   // u @ Wvu.T
  k_init<<<BATCH / RTI, NF, 0, stream>>>(uv, bv, Vt, s0[0], s1[0]);

  for (int t = 0; t < THERM + NSAMP; ++t) {
    uint32_t kh0, kh1, kv0, kv1;
    tf2x32(s0[1 + t], s1[1 + t], 0u, 0u, &kh0, &kh1);
    tf2x32(s0[1 + t], s1[1 + t], 0u, 1u, &kv0, &kv1);
    int* smp = (t >= THERM) ? out + (size_t)(t - THERM) * BATCH * NF : (int*)nullptr;
    // h = bern(k1, sigmoid(v @ Whv.T + uh + bh))
    k_phase<<<BATCH / RT, NF, 0, stream>>>(Vt, WhvT, uh, bh, Ht, (int*)nullptr, kh0, kh1);
    // v = bern(k2, sigmoid(h @ Whv + uv + bv)) ; emit sample when t>=THERM
    k_phase<<<BATCH / RT, NF, 0, stream>>>(Ht, Whv, uv, bv, Vt, smp, kv0, kv1);
  }
  (void)in_sizes; (void)n_in; (void)out_size; (void)ws_size;
}